// Round 2
// baseline (13582.358 us; speedup 1.0000x reference)
//
#include <hip/hip_runtime.h>

// TopKActivationMLP: B=16384, IN=1024, H=2048, K=256, NC=1000
//   h0 = relu(topk256(x @ W0^T + b0))
//   h1 = relu(topk256(h0 @ W1^T + b1))
//   out = h1 @ Wc^T + bc
//
// R1: fp64-accumulate GEMMs (float x float -> double products are EXACT) so
// the top-k selection matches the float64 numpy reference bit-for-decision.
// Top-k: 32-bit radix select on high bits of monotonic u64 key + exact
// 64-bit/index tie resolution among the rare high-32 collisions.

#define B_SZ 16384
#define IN_SZ 1024
#define H_SZ 2048
#define K_TOP 256
#define NC_SZ 1000

// ---------- fp64-accumulate GEMM: C[M,N] = A[M,Kd] @ Bt[N,Kd]^T + bias ----
// 64x64 tile, 256 threads, 4x4 doubles per thread, K-tile 16.
template <typename TA, typename TC>
__global__ __launch_bounds__(256) void gemm_bt_acc64(
    const TA* __restrict__ A, const float* __restrict__ Bt,
    const float* __restrict__ bias, TC* __restrict__ C,
    int M, int N, int Kd) {
  __shared__ double As[16][65];
  __shared__ double Bs[16][65];
  const int tid = threadIdx.x;
  const int tx = tid & 15;   // 16 thread-cols
  const int ty = tid >> 4;   // 16 thread-rows
  const int m0 = blockIdx.y * 64;
  const int n0 = blockIdx.x * 64;

  double acc[4][4];
#pragma unroll
  for (int i = 0; i < 4; ++i)
#pragma unroll
    for (int j = 0; j < 4; ++j) acc[i][j] = 0.0;

  for (int k0 = 0; k0 < Kd; k0 += 16) {
#pragma unroll
    for (int l = 0; l < 4; ++l) {
      const int idx = l * 256 + tid;
      const int rr = idx >> 4;   // 0..63
      const int kk = idx & 15;   // 0..15
      As[kk][rr] = (double)A[(size_t)(m0 + rr) * Kd + (k0 + kk)];
      Bs[kk][rr] = (n0 + rr < N)
                       ? (double)Bt[(size_t)(n0 + rr) * Kd + (k0 + kk)]
                       : 0.0;
    }
    __syncthreads();
#pragma unroll
    for (int kk = 0; kk < 16; ++kk) {
      double a[4], b[4];
#pragma unroll
      for (int i = 0; i < 4; ++i) a[i] = As[kk][ty * 4 + i];
#pragma unroll
      for (int j = 0; j < 4; ++j) b[j] = Bs[kk][tx * 4 + j];
#pragma unroll
      for (int i = 0; i < 4; ++i)
#pragma unroll
        for (int j = 0; j < 4; ++j) acc[i][j] = fma(a[i], b[j], acc[i][j]);
    }
    __syncthreads();
  }

#pragma unroll
  for (int i = 0; i < 4; ++i) {
    const int r = m0 + ty * 4 + i;
#pragma unroll
    for (int j = 0; j < 4; ++j) {
      const int c = n0 + tx * 4 + j;
      if (c < N) C[(size_t)r * N + c] = (TC)(acc[i][j] + (double)bias[c]);
    }
  }
}

__device__ __forceinline__ int blockReduceSum(int v, int* sred) {
#pragma unroll
  for (int o = 32; o > 0; o >>= 1) v += __shfl_down(v, o);
  const int tid = threadIdx.x;
  if ((tid & 63) == 0) sred[tid >> 6] = v;
  __syncthreads();
  int t = 0;
  if (tid < 4) t = sred[tid];
  t += __shfl_down(t, 2);
  t += __shfl_down(t, 1);
  if (tid == 0) sred[0] = t;
  __syncthreads();
  const int r = sred[0];
  __syncthreads();
  return r;
}

// Per-row top-K mask + ReLU, in place on double rows of 2048.
// One 256-thread block per row; 8 elements per thread.
__global__ __launch_bounds__(256) void topk_relu_f64(double* __restrict__ h) {
  __shared__ int sred[4];
  __shared__ int scnt;
  __shared__ unsigned long long ckey[128];
  __shared__ int cidx[128];
  const int tid = threadIdx.x;
  double* hr = h + (size_t)blockIdx.x * H_SZ;

  double myv[8];
  unsigned long long myk64[8];
  unsigned int myk[8];
#pragma unroll
  for (int l = 0; l < 8; ++l) {
    const int i = l * 256 + tid;
    const double v = hr[i];
    myv[l] = v;
    unsigned long long b = (unsigned long long)__double_as_longlong(v);
    // monotonic increasing map
    unsigned long long u =
        (b & 0x8000000000000000ULL) ? ~b : (b | 0x8000000000000000ULL);
    myk64[l] = u;
    myk[l] = (unsigned int)(u >> 32);
  }

  // radix select the K-th largest high-32 key
  unsigned int prefix = 0;
  int remaining = K_TOP;
  for (int b = 31; b >= 0; --b) {
    const unsigned int bit = 1u << b;
    const unsigned int hi_mask = ~((bit << 1) - 1u);  // bits above b (b=31 -> 0)
    int cnt = 0;
#pragma unroll
    for (int l = 0; l < 8; ++l) {
      const unsigned int u = myk[l];
      cnt += (((u & hi_mask) == prefix) && (u & bit)) ? 1 : 0;
    }
    const int total = blockReduceSum(cnt, sred);
    if (total >= remaining) prefix |= bit;
    else remaining -= total;
  }
  const unsigned int T = prefix;

  int cg = 0, ce = 0;
#pragma unroll
  for (int l = 0; l < 8; ++l) {
    cg += (myk[l] > T) ? 1 : 0;
    ce += (myk[l] == T) ? 1 : 0;
  }
  const int count_gt = blockReduceSum(cg, sred);
  const int count_eq = blockReduceSum(ce, sred);
  const int need_eq = K_TOP - count_gt;  // >= 1 by select invariant

  bool keep[8];
#pragma unroll
  for (int l = 0; l < 8; ++l) keep[l] = (myk[l] > T);

  if (count_eq == need_eq) {
#pragma unroll
    for (int l = 0; l < 8; ++l) keep[l] = keep[l] || (myk[l] == T);
  } else {
    // rare: multiple elements collide on high-32 bits at the boundary.
    // Resolve exactly with full 64-bit keys, ties by lowest index (stable
    // descending sort semantics of jax.lax.top_k).
    if (tid == 0) scnt = 0;
    __syncthreads();
    int mypos[8];
#pragma unroll
    for (int l = 0; l < 8; ++l) mypos[l] = -1;
#pragma unroll
    for (int l = 0; l < 8; ++l) {
      if (myk[l] == T) {
        const int p = atomicAdd(&scnt, 1);
        if (p < 128) {
          ckey[p] = myk64[l];
          cidx[p] = l * 256 + tid;
          mypos[l] = p;
        }
      }
    }
    __syncthreads();
    const int c = (scnt < 128) ? scnt : 128;
#pragma unroll
    for (int l = 0; l < 8; ++l) {
      if (mypos[l] >= 0) {
        const unsigned long long k = ckey[mypos[l]];
        const int ii = cidx[mypos[l]];
        int rank = 0;
        for (int j = 0; j < c; ++j) {
          rank += ((ckey[j] > k) || (ckey[j] == k && cidx[j] < ii)) ? 1 : 0;
        }
        keep[l] = (rank < need_eq);
      }
    }
  }

#pragma unroll
  for (int l = 0; l < 8; ++l) {
    const int i = l * 256 + tid;
    const double v = myv[l];
    hr[i] = (keep[l] && v > 0.0) ? v : 0.0;
  }
}

extern "C" void kernel_launch(void* const* d_in, const int* in_sizes, int n_in,
                              void* d_out, int out_size, void* d_ws, size_t ws_size,
                              hipStream_t stream) {
  const float* x  = (const float*)d_in[0];
  const float* W0 = (const float*)d_in[1];
  const float* b0 = (const float*)d_in[2];
  const float* W1 = (const float*)d_in[3];
  const float* b1 = (const float*)d_in[4];
  const float* Wc = (const float*)d_in[5];
  const float* bc = (const float*)d_in[6];
  float* out = (float*)d_out;

  // Need two double buffers [chunkB, H]: h0 and h1.
  int chunkB = B_SZ;
  while ((size_t)chunkB * H_SZ * sizeof(double) * 2 > ws_size && chunkB > 64)
    chunkB >>= 1;

  double* h0 = (double*)d_ws;
  double* h1 = h0 + (size_t)chunkB * H_SZ;

  const dim3 blk(256);
  for (int m0 = 0; m0 < B_SZ; m0 += chunkB) {
    const int M = chunkB;
    const dim3 g01(H_SZ / 64, M / 64);
    gemm_bt_acc64<float, double><<<g01, blk, 0, stream>>>(
        x + (size_t)m0 * IN_SZ, W0, b0, h0, M, H_SZ, IN_SZ);
    topk_relu_f64<<<dim3(M), blk, 0, stream>>>(h0);
    gemm_bt_acc64<double, double><<<g01, blk, 0, stream>>>(
        h0, W1, b1, h1, M, H_SZ, H_SZ);
    topk_relu_f64<<<dim3(M), blk, 0, stream>>>(h1);
    const dim3 g2((NC_SZ + 63) / 64, M / 64);
    gemm_bt_acc64<double, float><<<g2, blk, 0, stream>>>(
        h1, Wc, bc, out + (size_t)m0 * NC_SZ, M, NC_SZ, H_SZ);
  }
}

// Round 3
// 7623.348 us; speedup vs baseline: 1.7817x; 1.7817x over previous
//
#include <hip/hip_runtime.h>

// TopKActivationMLP: B=16384, IN=1024, H=2048, K=256, NC=1000
//   h0 = relu(topk256(x @ W0^T + b0))
//   h1 = relu(topk256(h0 @ W1^T + b1))
//   out = h1 @ Wc^T + bc
//
// R2: fp64-accumulate GEMM restructured for zero LDS bank conflicts:
//  - 128x64 tile, 256 threads, 8x4 doubles/thread with STRIDE-16 ownership
//    (thread (tym,tx) owns rows tym+16i, cols tx+16j) so fragment reads are
//    4-lane-contiguous + 16-lane-broadcast => conflict-free.
//  - staging rows padded to 130/66 doubles so write banks rotate with kk.
// Top-k decisions remain fp64-exact (same accumulation order as R1).

#define B_SZ 16384
#define IN_SZ 1024
#define H_SZ 2048
#define K_TOP 256
#define NC_SZ 1000

// ---------- fp64-accumulate GEMM: C[M,N] = A[M,Kd] @ Bt[N,Kd]^T + bias ----
// BM=128, BN=64, BK=16; 256 threads; 8x4 doubles per thread (stride-16).
template <typename TA, typename TC>
__global__ __launch_bounds__(256, 4) void gemm_bt_v2(
    const TA* __restrict__ A, const float* __restrict__ Bt,
    const float* __restrict__ bias, TC* __restrict__ C,
    int M, int N, int Kd) {
  __shared__ double As[16][130];  // [kk][m], pad->row stride 130 dbl
  __shared__ double Bs[16][66];   // [kk][n], pad->row stride 66 dbl
  const int tid = threadIdx.x;
  const int tx = tid & 15;    // n-lane: owns cols tx + 16j
  const int tym = tid >> 4;   // m-lane: owns rows tym + 16i
  const int m0 = blockIdx.y * 128;
  const int n0 = blockIdx.x * 64;

  double acc[8][4];
#pragma unroll
  for (int i = 0; i < 8; ++i)
#pragma unroll
    for (int j = 0; j < 4; ++j) acc[i][j] = 0.0;

  for (int k0 = 0; k0 < Kd; k0 += 16) {
    // stage A tile: 128x16 = 2048 elems, 8 per thread.
    // lane pattern: kk = tid&15 (consecutive k -> coalesced 128B global reads)
#pragma unroll
    for (int l = 0; l < 8; ++l) {
      const int idx = l * 256 + tid;
      const int rr = idx >> 4;   // 0..127
      const int kk = idx & 15;
      As[kk][rr] = (double)A[(size_t)(m0 + rr) * Kd + (k0 + kk)];
    }
    // stage B tile: 64x16 = 1024 elems, 4 per thread.
#pragma unroll
    for (int l = 0; l < 4; ++l) {
      const int idx = l * 256 + tid;
      const int rr = idx >> 4;   // 0..63
      const int kk = idx & 15;
      Bs[kk][rr] = (n0 + rr < N)
                       ? (double)Bt[(size_t)(n0 + rr) * Kd + (k0 + kk)]
                       : 0.0;
    }
    __syncthreads();

#pragma unroll 4
    for (int kk = 0; kk < 16; ++kk) {
      double a[8], b[4];
#pragma unroll
      for (int i = 0; i < 8; ++i) a[i] = As[kk][tym + 16 * i];
#pragma unroll
      for (int j = 0; j < 4; ++j) b[j] = Bs[kk][tx + 16 * j];
#pragma unroll
      for (int i = 0; i < 8; ++i)
#pragma unroll
        for (int j = 0; j < 4; ++j) acc[i][j] = fma(a[i], b[j], acc[i][j]);
    }
    __syncthreads();
  }

#pragma unroll
  for (int i = 0; i < 8; ++i) {
    const int r = m0 + tym + 16 * i;
#pragma unroll
    for (int j = 0; j < 4; ++j) {
      const int c = n0 + tx + 16 * j;
      if (c < N) C[(size_t)r * N + c] = (TC)(acc[i][j] + (double)bias[c]);
    }
  }
}

__device__ __forceinline__ int blockReduceSum(int v, int* sred) {
#pragma unroll
  for (int o = 32; o > 0; o >>= 1) v += __shfl_down(v, o);
  const int tid = threadIdx.x;
  if ((tid & 63) == 0) sred[tid >> 6] = v;
  __syncthreads();
  int t = 0;
  if (tid < 4) t = sred[tid];
  t += __shfl_down(t, 2);
  t += __shfl_down(t, 1);
  if (tid == 0) sred[0] = t;
  __syncthreads();
  const int r = sred[0];
  __syncthreads();
  return r;
}

// Per-row top-K mask + ReLU, in place on double rows of 2048.
__global__ __launch_bounds__(256) void topk_relu_f64(double* __restrict__ h) {
  __shared__ int sred[4];
  __shared__ int scnt;
  __shared__ unsigned long long ckey[128];
  __shared__ int cidx[128];
  const int tid = threadIdx.x;
  double* hr = h + (size_t)blockIdx.x * H_SZ;

  double myv[8];
  unsigned long long myk64[8];
  unsigned int myk[8];
#pragma unroll
  for (int l = 0; l < 8; ++l) {
    const int i = l * 256 + tid;
    const double v = hr[i];
    myv[l] = v;
    unsigned long long b = (unsigned long long)__double_as_longlong(v);
    unsigned long long u =
        (b & 0x8000000000000000ULL) ? ~b : (b | 0x8000000000000000ULL);
    myk64[l] = u;
    myk[l] = (unsigned int)(u >> 32);
  }

  unsigned int prefix = 0;
  int remaining = K_TOP;
  for (int b = 31; b >= 0; --b) {
    const unsigned int bit = 1u << b;
    const unsigned int hi_mask = ~((bit << 1) - 1u);
    int cnt = 0;
#pragma unroll
    for (int l = 0; l < 8; ++l) {
      const unsigned int u = myk[l];
      cnt += (((u & hi_mask) == prefix) && (u & bit)) ? 1 : 0;
    }
    const int total = blockReduceSum(cnt, sred);
    if (total >= remaining) prefix |= bit;
    else remaining -= total;
  }
  const unsigned int T = prefix;

  int cg = 0, ce = 0;
#pragma unroll
  for (int l = 0; l < 8; ++l) {
    cg += (myk[l] > T) ? 1 : 0;
    ce += (myk[l] == T) ? 1 : 0;
  }
  const int count_gt = blockReduceSum(cg, sred);
  const int count_eq = blockReduceSum(ce, sred);
  const int need_eq = K_TOP - count_gt;

  bool keep[8];
#pragma unroll
  for (int l = 0; l < 8; ++l) keep[l] = (myk[l] > T);

  if (count_eq == need_eq) {
#pragma unroll
    for (int l = 0; l < 8; ++l) keep[l] = keep[l] || (myk[l] == T);
  } else {
    // rare: high-32 collision at the boundary -> exact 64-bit + index resolve
    if (tid == 0) scnt = 0;
    __syncthreads();
    int mypos[8];
#pragma unroll
    for (int l = 0; l < 8; ++l) mypos[l] = -1;
#pragma unroll
    for (int l = 0; l < 8; ++l) {
      if (myk[l] == T) {
        const int p = atomicAdd(&scnt, 1);
        if (p < 128) {
          ckey[p] = myk64[l];
          cidx[p] = l * 256 + tid;
          mypos[l] = p;
        }
      }
    }
    __syncthreads();
    const int c = (scnt < 128) ? scnt : 128;
#pragma unroll
    for (int l = 0; l < 8; ++l) {
      if (mypos[l] >= 0) {
        const unsigned long long k = ckey[mypos[l]];
        const int ii = cidx[mypos[l]];
        int rank = 0;
        for (int j = 0; j < c; ++j) {
          rank += ((ckey[j] > k) || (ckey[j] == k && cidx[j] < ii)) ? 1 : 0;
        }
        keep[l] = (rank < need_eq);
      }
    }
  }

#pragma unroll
  for (int l = 0; l < 8; ++l) {
    const int i = l * 256 + tid;
    const double v = myv[l];
    hr[i] = (keep[l] && v > 0.0) ? v : 0.0;
  }
}

extern "C" void kernel_launch(void* const* d_in, const int* in_sizes, int n_in,
                              void* d_out, int out_size, void* d_ws, size_t ws_size,
                              hipStream_t stream) {
  const float* x  = (const float*)d_in[0];
  const float* W0 = (const float*)d_in[1];
  const float* b0 = (const float*)d_in[2];
  const float* W1 = (const float*)d_in[3];
  const float* b1 = (const float*)d_in[4];
  const float* Wc = (const float*)d_in[5];
  const float* bc = (const float*)d_in[6];
  float* out = (float*)d_out;

  int chunkB = B_SZ;
  while ((size_t)chunkB * H_SZ * sizeof(double) * 2 > ws_size && chunkB > 128)
    chunkB >>= 1;

  double* h0 = (double*)d_ws;
  double* h1 = h0 + (size_t)chunkB * H_SZ;

  const dim3 blk(256);
  for (int m0 = 0; m0 < B_SZ; m0 += chunkB) {
    const int M = chunkB;
    const dim3 g01(H_SZ / 64, M / 128);
    gemm_bt_v2<float, double><<<g01, blk, 0, stream>>>(
        x + (size_t)m0 * IN_SZ, W0, b0, h0, M, H_SZ, IN_SZ);
    topk_relu_f64<<<dim3(M), blk, 0, stream>>>(h0);
    gemm_bt_v2<double, double><<<g01, blk, 0, stream>>>(
        h0, W1, b1, h1, M, H_SZ, H_SZ);
    topk_relu_f64<<<dim3(M), blk, 0, stream>>>(h1);
    const dim3 g2((NC_SZ + 63) / 64, M / 128);
    gemm_bt_v2<double, float><<<g2, blk, 0, stream>>>(
        h1, Wc, bc, out + (size_t)m0 * NC_SZ, M, NC_SZ, H_SZ);
  }
}